// Round 6
// baseline (1973.469 us; speedup 1.0000x reference)
//
#include <hip/hip_runtime.h>
#include <math.h>

#define EPS_YAT (1.0f/137.0f)

__device__ __forceinline__ float4 ld4(const float* p) { return *(const float4*)p; }

// Swizzled 64x64 tile, float4-slot XOR (row>>2): conflict-free for all hot
// patterns here (broadcast row reads, 4-strided rows at fixed slot,
// contiguous row writes). 16 KB/tile. (0 conflicts measured R3/R4/R5.)
__device__ __forceinline__ float4* T4(float* t, int row, int s4) {
    return (float4*)(t + row * 64 + ((s4 ^ (row >> 2)) & 15) * 4);
}

// ---- column norms of W [K,N] -> wn[N]; 64 cols/block, 4 k-slices ----
__global__ void colnorm_kernel(const float* __restrict__ W, float* __restrict__ wn,
                               int K, int N) {
    __shared__ float sm[256];
    const int col = blockIdx.x * 64 + (threadIdx.x & 63);
    const int slc = threadIdx.x >> 6;           // 0..3
    const int kper = K >> 2;
    float s = 0.f;
    if (col < N) {
        for (int k = slc * kper; k < (slc + 1) * kper; ++k) {
            float w = W[(size_t)k * N + col];
            s += w * w;
        }
    }
    sm[threadIdx.x] = s;
    __syncthreads();
    if (threadIdx.x < 64 && col < N)
        wn[col] = sm[threadIdx.x] + sm[threadIdx.x + 64] + sm[threadIdx.x + 128] + sm[threadIdx.x + 192];
}

// ---- row norms of X [R,K] -> rn[R]; one wave per row, 4 rows/block ----
__global__ void rownorm_kernel(const float* __restrict__ X, float* __restrict__ rn, int K) {
    int wave = threadIdx.x >> 6;
    int lane = threadIdx.x & 63;
    int row = blockIdx.x * 4 + wave;
    const float* xr = X + (size_t)row * K;
    float s = 0.f;
    for (int k = lane * 4; k < K; k += 256) {
        float4 v = ld4(xr + k);
        s += v.x * v.x + v.y * v.y + v.z * v.z + v.w * v.w;
    }
    for (int off = 32; off; off >>= 1) s += __shfl_down(s, off);
    if (lane == 0) rn[row] = s;
}

// ---- q/k norms from qkv [B,T,3C]: qn/kn indexed [b*H+h][t] ----
__global__ void qknorm_kernel(const float* __restrict__ qkv, float* __restrict__ qn,
                              float* __restrict__ kn) {
    int gid = blockIdx.x * 256 + threadIdx.x;
    int lane = gid & 15;
    int idx = gid >> 4;                  // 0..98303
    int which = (idx >= 49152) ? 1 : 0;  // 0=q, 1=k
    int r = idx - which * 49152;
    int t = r & 1023;
    int bh = r >> 10;
    int h = bh % 12, b = bh / 12;
    const float* p = qkv + (size_t)(b * 1024 + t) * 2304 + which * 768 + h * 64 + lane * 4;
    float4 v = ld4(p);
    float s = v.x * v.x + v.y * v.y + v.z * v.z + v.w * v.w;
    s += __shfl_xor(s, 1, 16);
    s += __shfl_xor(s, 2, 16);
    s += __shfl_xor(s, 4, 16);
    s += __shfl_xor(s, 8, 16);
    if (lane == 0) (which ? kn : qn)[r] = s;
}

// ---- yat GEMM: 128x128 tile, 8x8 micro (cols split as cl / cl+64 so Bs
// reads are <=2-way bank-aliased), reg-prefetch pipelined k-loop.
// 0.5 B(LDS)/FLOP -> FMA-bound (old 64x128/4x8 was LDS-bound at 0.75).
__global__ __launch_bounds__(256, 2)
void yat_gemm_kernel(const float* __restrict__ A, const float* __restrict__ W,
                     const float* __restrict__ bias, const float* __restrict__ xn,
                     const float* __restrict__ wn, const float* __restrict__ alphap,
                     const float Fdim, float* __restrict__ out,
                     const int M, const int N, const int K) {
    __shared__ float As[32][132];  // [k][m], stride 132: A-writes 2-way, reads broadcast
    __shared__ float Bs[32][132];  // [k][n]
    const int tid = threadIdx.x;
    const int m0 = blockIdx.y << 7;
    const int n0 = blockIdx.x << 7;
    const int tr = tid >> 4;        // 0..15
    const int tc = tid & 15;        // 0..15
    const int r8 = tr << 3;         // 0..120
    const int cl = tc << 2;         // 0..60  (second col group at cl+64)
    float acc[8][8] = {};

    // staging assignment
    const int ar = tid >> 1;               // A row 0..127
    const int ac = (tid & 1) << 4;         // A col base (floats): 0 or 16
    const int br = tid >> 3;               // B row 0..31
    const int bc = (tid & 7) << 4;         // B col base (floats)

    // prologue: stage k-tile 0
    float4 aS[4], bS[4];
    #pragma unroll
    for (int c = 0; c < 4; ++c) {
        aS[c] = ld4(A + (size_t)(m0 + ar) * K + ac + (c << 2));
        bS[c] = ld4(W + (size_t)br * N + n0 + bc + (c << 2));
    }

    for (int k0 = 0; k0 < K; k0 += 32) {
        __syncthreads();  // prev compute done with LDS
        #pragma unroll
        for (int c = 0; c < 4; ++c) {
            As[ac + (c << 2) + 0][ar] = aS[c].x;
            As[ac + (c << 2) + 1][ar] = aS[c].y;
            As[ac + (c << 2) + 2][ar] = aS[c].z;
            As[ac + (c << 2) + 3][ar] = aS[c].w;
            *(float4*)&Bs[br][bc + (c << 2)] = bS[c];
        }
        __syncthreads();

        if (k0 + 32 < K) {  // prefetch next k-tile; vmcnt waits land next iter
            #pragma unroll
            for (int c = 0; c < 4; ++c) {
                aS[c] = ld4(A + (size_t)(m0 + ar) * K + k0 + 32 + ac + (c << 2));
                bS[c] = ld4(W + (size_t)(k0 + 32 + br) * N + n0 + bc + (c << 2));
            }
        }

        #pragma unroll
        for (int kk = 0; kk < 32; ++kk) {
            float4 a0 = *(const float4*)&As[kk][r8];
            float4 a1 = *(const float4*)&As[kk][r8 + 4];
            float4 b0 = *(const float4*)&Bs[kk][cl];
            float4 b1 = *(const float4*)&Bs[kk][cl + 64];
            float aa[8] = {a0.x, a0.y, a0.z, a0.w, a1.x, a1.y, a1.z, a1.w};
            float bb[8] = {b0.x, b0.y, b0.z, b0.w, b1.x, b1.y, b1.z, b1.w};
            #pragma unroll
            for (int i = 0; i < 8; ++i)
                #pragma unroll
                for (int j = 0; j < 8; ++j)
                    acc[i][j] += aa[i] * bb[j];
        }
    }

    const float scale = powf(sqrtf(Fdim) / log1pf(Fdim), *alphap);
    #pragma unroll
    for (int i = 0; i < 8; ++i) {
        const int m = m0 + r8 + i;
        const float xnm = xn[m];
        float o[8];
        #pragma unroll
        for (int j = 0; j < 8; ++j) {
            const int n = n0 + ((j < 4) ? (cl + j) : (64 + cl + j - 4));
            float d = acc[i][j];
            float den = xnm + wn[n] - 2.f * d + EPS_YAT;
            o[j] = (d * d / den + bias[n]) * scale;
        }
        float* op = out + (size_t)m * N + n0 + cl;
        *(float4*)op        = make_float4(o[0], o[1], o[2], o[3]);
        *(float4*)(op + 64) = make_float4(o[4], o[5], o[6], o[7]);
    }
}

// ======================= flash attention (yat score) ========================
// Monolithic 64-row q-tile per block, K/V global->reg prefetch one iteration
// ahead (R5: 2.5x win). R6 changes: v_rcp instead of VCC-serialized fp32 div
// (16/thread/iter), kns hoisted to one ds_read_b128/iter, arithmetic qt (no
// dynamically-indexed local array). LDS 48.5 KB, launch_bounds(256,3).
__global__ __launch_bounds__(256, 3)
void yat_flash_kernel(const float* __restrict__ qkv, const float* __restrict__ qn,
                      const float* __restrict__ kn, float* __restrict__ out) {
    __shared__ __align__(16) float Qs[4096], Ks[4096], Vs[4096];
    __shared__ __align__(16) float kns[64];
    float* Ps = Ks;  // Ks dead once S is computed
    const int tid = threadIdx.x;
    const int L = blockIdx.x;        // 0..767
    const int u = L / 48;            // 0..15
    // interleaved qt: even u -> 15-u/2 (heavy), odd u -> u/2 (light)
    const int qt = (u & 1) ? (u >> 1) : (15 - (u >> 1));
    const int bh = L % 48;
    const int h = bh % 12, b = bh / 12;
    const int lr = tid >> 4;         // 0..15
    const int lsl = tid & 15;        // float4 slot
    const int lc = lsl << 2;
    const size_t base = (size_t)b * 2359296 + h * 64;  // b*1024*2304

    #pragma unroll
    for (int l = 0; l < 4; ++l) {
        int row = lr + l * 16;
        *T4(Qs, row, lsl) = ld4(qkv + base + (size_t)((qt << 6) + row) * 2304 + lc);
    }

    const int r4 = lr << 2;          // 0..60
    const int c4 = lc;               // 0..60
    const int rs0 = lr;
    const int cs0 = lsl;
    float qnr[4];
    #pragma unroll
    for (int i = 0; i < 4; ++i) qnr[i] = qn[bh * 1024 + (qt << 6) + r4 + i];

    float acc[4][4] = {};
    float mrow[4] = {-3e38f, -3e38f, -3e38f, -3e38f};
    float lrow[4] = {0.f, 0.f, 0.f, 0.f};

    // stage kt=0 K/V into registers
    float4 kS[4], vS[4];
    #pragma unroll
    for (int l = 0; l < 4; ++l) {
        size_t rb = base + (size_t)(lr + l * 16) * 2304;
        kS[l] = ld4(qkv + rb + 768 + lc);
        vS[l] = ld4(qkv + rb + 1536 + lc);
    }
    float knS = (tid < 64) ? kn[bh * 1024 + tid] : 0.f;

    for (int kt = 0; kt <= qt; ++kt) {
        __syncthreads();  // prior PV reads (Ps=Ks, Vs) done before overwrite
        #pragma unroll
        for (int l = 0; l < 4; ++l) {
            int row = lr + l * 16;
            *T4(Ks, row, lsl) = kS[l];
            *T4(Vs, row, lsl) = vS[l];
        }
        if (tid < 64) kns[tid] = knS;
        __syncthreads();

        if (kt < qt) {  // prefetch kt+1 (block-uniform)
            #pragma unroll
            for (int l = 0; l < 4; ++l) {
                size_t rb = base + (size_t)(((kt + 1) << 6) + lr + l * 16) * 2304;
                kS[l] = ld4(qkv + rb + 768 + lc);
                vS[l] = ld4(qkv + rb + 1536 + lc);
            }
            if (tid < 64) knS = kn[bh * 1024 + ((kt + 1) << 6) + tid];
        }

        // hoist the 4 k-norms this thread needs (constant over i)
        const float4 kn4 = *(const float4*)&kns[c4];

        // ---- S = Q K^T ----
        float s[4][4] = {};
        #pragma unroll
        for (int d4 = 0; d4 < 16; ++d4) {
            float4 aR[4], bR[4];
            #pragma unroll
            for (int i = 0; i < 4; ++i)
                aR[i] = *(const float4*)(Qs + (r4 + i) * 64 + ((d4 ^ rs0) & 15) * 4);
            #pragma unroll
            for (int j = 0; j < 4; ++j)
                bR[j] = *(const float4*)(Ks + (c4 + j) * 64 + ((d4 ^ cs0) & 15) * 4);
            #pragma unroll
            for (int i = 0; i < 4; ++i)
                #pragma unroll
                for (int j = 0; j < 4; ++j)
                    s[i][j] += aR[i].x * bR[j].x + aR[i].y * bR[j].y +
                               aR[i].z * bR[j].z + aR[i].w * bR[j].w;
        }
        __syncthreads();  // Ks reads done; Ps may overwrite

        // ---- yat score + causal mask + online softmax; P -> LDS ----
        const bool diag = (kt == qt);
        const float knv[4] = {kn4.x, kn4.y, kn4.z, kn4.w};
        #pragma unroll
        for (int i = 0; i < 4; ++i) {
            float mm = -3e38f;
            #pragma unroll
            for (int j = 0; j < 4; ++j) {
                float sv = s[i][j] * 0.125f;
                float den = qnr[i] + knv[j] - 2.f * sv + EPS_YAT;  // >= eps > 0
                float v = sv * sv * __builtin_amdgcn_rcpf(den);    // no VCC chain
                if (diag && (c4 + j > r4 + i)) v = -3e38f;
                s[i][j] = v;
                mm = fmaxf(mm, v);
            }
            mm = fmaxf(mm, __shfl_xor(mm, 8, 16));
            mm = fmaxf(mm, __shfl_xor(mm, 4, 16));
            mm = fmaxf(mm, __shfl_xor(mm, 2, 16));
            mm = fmaxf(mm, __shfl_xor(mm, 1, 16));
            const float mnew = fmaxf(mrow[i], mm);
            const float al = __expf(mrow[i] - mnew);
            mrow[i] = mnew;
            float rs = 0.f;
            #pragma unroll
            for (int j = 0; j < 4; ++j) {
                float p = __expf(s[i][j] - mnew);  // masked -> 0
                s[i][j] = p;
                rs += p;
            }
            rs += __shfl_xor(rs, 8, 16);
            rs += __shfl_xor(rs, 4, 16);
            rs += __shfl_xor(rs, 2, 16);
            rs += __shfl_xor(rs, 1, 16);
            lrow[i] = lrow[i] * al + rs;
            acc[i][0] *= al; acc[i][1] *= al; acc[i][2] *= al; acc[i][3] *= al;
            *T4(Ps, r4 + i, lsl) = make_float4(s[i][0], s[i][1], s[i][2], s[i][3]);
        }
        __syncthreads();

        // ---- O += P V ----
        #pragma unroll
        for (int j4 = 0; j4 < 16; ++j4) {
            float4 pR[4], vR[4];
            #pragma unroll
            for (int i = 0; i < 4; ++i)
                pR[i] = *(const float4*)(Ps + (r4 + i) * 64 + ((j4 ^ rs0) & 15) * 4);
            #pragma unroll
            for (int t2 = 0; t2 < 4; ++t2)
                vR[t2] = *(const float4*)(Vs + ((j4 << 2) + t2) * 64 + ((cs0 ^ j4) & 15) * 4);
            #pragma unroll
            for (int i = 0; i < 4; ++i) {
                acc[i][0] += pR[i].x * vR[0].x + pR[i].y * vR[1].x + pR[i].z * vR[2].x + pR[i].w * vR[3].x;
                acc[i][1] += pR[i].x * vR[0].y + pR[i].y * vR[1].y + pR[i].z * vR[2].y + pR[i].w * vR[3].y;
                acc[i][2] += pR[i].x * vR[0].z + pR[i].y * vR[1].z + pR[i].z * vR[2].z + pR[i].w * vR[3].z;
                acc[i][3] += pR[i].x * vR[0].w + pR[i].y * vR[1].w + pR[i].z * vR[2].w + pR[i].w * vR[3].w;
            }
        }
    }

    #pragma unroll
    for (int i = 0; i < 4; ++i) {
        float inv = __builtin_amdgcn_rcpf(lrow[i]);  // l >= exp(0) scale, safe
        *(float4*)(out + (size_t)(b * 1024 + (qt << 6) + r4 + i) * 768 + h * 64 + c4) =
            make_float4(acc[i][0] * inv, acc[i][1] * inv, acc[i][2] * inv, acc[i][3] * inv);
    }
}

extern "C" void kernel_launch(void* const* d_in, const int* in_sizes, int n_in,
                              void* d_out, int out_size, void* d_ws, size_t ws_size,
                              hipStream_t stream) {
    const float* x          = (const float*)d_in[0];
    // d_in[1] = mask (causal, known structure — unused)
    const float* W_attn     = (const float*)d_in[2];
    const float* b_attn     = (const float*)d_in[3];
    const float* alpha_attn = (const float*)d_in[4];
    const float* W_proj     = (const float*)d_in[5];
    const float* b_proj     = (const float*)d_in[6];
    const float* alpha_proj = (const float*)d_in[7];

    float* ws       = (float*)d_ws;
    float* qkv      = ws;                 // 4*1024*2304 = 9437184
    float* attn_out = ws + 9437184;       // 4*1024*768  = 3145728
    float* xn       = ws + 12582912;      // 4096
    float* an       = ws + 12587008;      // 4096
    float* wn_attn  = ws + 12591104;      // 2304
    float* wn_proj  = ws + 12593408;      // 768
    float* qn       = ws + 12594176;      // 49152
    float* kn       = ws + 12643328;      // 49152  (end: 12692480 floats ~50.8 MB)

    colnorm_kernel<<<36, 256, 0, stream>>>(W_attn, wn_attn, 768, 2304);
    colnorm_kernel<<<12, 256, 0, stream>>>(W_proj, wn_proj, 768, 768);
    rownorm_kernel<<<1024, 256, 0, stream>>>(x, xn, 768);
    yat_gemm_kernel<<<dim3(18, 32), 256, 0, stream>>>(
        x, W_attn, b_attn, xn, wn_attn, alpha_attn, 2304.f, qkv, 4096, 2304, 768);
    qknorm_kernel<<<6144, 256, 0, stream>>>(qkv, qn, kn);
    yat_flash_kernel<<<768, 256, 0, stream>>>(qkv, qn, kn, attn_out);
    rownorm_kernel<<<1024, 256, 0, stream>>>(attn_out, an, 768);
    yat_gemm_kernel<<<dim3(6, 32), 256, 0, stream>>>(
        attn_out, W_proj, b_proj, an, wn_proj, alpha_proj, 768.f, (float*)d_out, 4096, 768, 768);
}

// Round 7
// 1119.011 us; speedup vs baseline: 1.7636x; 1.7636x over previous
//
#include <hip/hip_runtime.h>
#include <math.h>

#define EPS_YAT (1.0f/137.0f)

__device__ __forceinline__ float4 ld4(const float* p) { return *(const float4*)p; }

// Swizzled 64x64 tile, float4-slot XOR (row>>2): conflict-free for all hot
// patterns here (broadcast row reads, 4-strided rows at fixed slot,
// contiguous row writes). 16 KB/tile. (0 conflicts measured R3/R4/R5.)
__device__ __forceinline__ float4* T4(float* t, int row, int s4) {
    return (float4*)(t + row * 64 + ((s4 ^ (row >> 2)) & 15) * 4);
}

// ---- column norms of W [K,N] -> wn[N]; 64 cols/block, 4 k-slices ----
__global__ void colnorm_kernel(const float* __restrict__ W, float* __restrict__ wn,
                               int K, int N) {
    __shared__ float sm[256];
    const int col = blockIdx.x * 64 + (threadIdx.x & 63);
    const int slc = threadIdx.x >> 6;           // 0..3
    const int kper = K >> 2;
    float s = 0.f;
    if (col < N) {
        for (int k = slc * kper; k < (slc + 1) * kper; ++k) {
            float w = W[(size_t)k * N + col];
            s += w * w;
        }
    }
    sm[threadIdx.x] = s;
    __syncthreads();
    if (threadIdx.x < 64 && col < N)
        wn[col] = sm[threadIdx.x] + sm[threadIdx.x + 64] + sm[threadIdx.x + 128] + sm[threadIdx.x + 192];
}

// ---- row norms of X [R,K] -> rn[R]; one wave per row, 4 rows/block ----
__global__ void rownorm_kernel(const float* __restrict__ X, float* __restrict__ rn, int K) {
    int wave = threadIdx.x >> 6;
    int lane = threadIdx.x & 63;
    int row = blockIdx.x * 4 + wave;
    const float* xr = X + (size_t)row * K;
    float s = 0.f;
    for (int k = lane * 4; k < K; k += 256) {
        float4 v = ld4(xr + k);
        s += v.x * v.x + v.y * v.y + v.z * v.z + v.w * v.w;
    }
    for (int off = 32; off; off >>= 1) s += __shfl_down(s, off);
    if (lane == 0) rn[row] = s;
}

// ---- q/k norms from qkv [B,T,3C]: qn/kn indexed [b*H+h][t] ----
__global__ void qknorm_kernel(const float* __restrict__ qkv, float* __restrict__ qn,
                              float* __restrict__ kn) {
    int gid = blockIdx.x * 256 + threadIdx.x;
    int lane = gid & 15;
    int idx = gid >> 4;                  // 0..98303
    int which = (idx >= 49152) ? 1 : 0;  // 0=q, 1=k
    int r = idx - which * 49152;
    int t = r & 1023;
    int bh = r >> 10;
    int h = bh % 12, b = bh / 12;
    const float* p = qkv + (size_t)(b * 1024 + t) * 2304 + which * 768 + h * 64 + lane * 4;
    float4 v = ld4(p);
    float s = v.x * v.x + v.y * v.y + v.z * v.z + v.w * v.w;
    s += __shfl_xor(s, 1, 16);
    s += __shfl_xor(s, 2, 16);
    s += __shfl_xor(s, 4, 16);
    s += __shfl_xor(s, 8, 16);
    if (lane == 0) (which ? kn : qn)[r] = s;
}

// ---- yat GEMM: 128x128 tile, 8x8 micro (cols split as cl / cl+64 so Bs
// reads are <=2-way bank-aliased), reg-prefetch pipelined k-loop. (R6: kept —
// rest-of-pipeline went 495 -> 415 us with this version.)
__global__ __launch_bounds__(256, 2)
void yat_gemm_kernel(const float* __restrict__ A, const float* __restrict__ W,
                     const float* __restrict__ bias, const float* __restrict__ xn,
                     const float* __restrict__ wn, const float* __restrict__ alphap,
                     const float Fdim, float* __restrict__ out,
                     const int M, const int N, const int K) {
    __shared__ float As[32][132];  // [k][m]
    __shared__ float Bs[32][132];  // [k][n]
    const int tid = threadIdx.x;
    const int m0 = blockIdx.y << 7;
    const int n0 = blockIdx.x << 7;
    const int tr = tid >> 4;        // 0..15
    const int tc = tid & 15;        // 0..15
    const int r8 = tr << 3;         // 0..120
    const int cl = tc << 2;         // 0..60  (second col group at cl+64)
    float acc[8][8] = {};

    const int ar = tid >> 1;               // A row 0..127
    const int ac = (tid & 1) << 4;         // A col base (floats): 0 or 16
    const int br = tid >> 3;               // B row 0..31
    const int bc = (tid & 7) << 4;         // B col base (floats)

    float4 aS[4], bS[4];
    #pragma unroll
    for (int c = 0; c < 4; ++c) {
        aS[c] = ld4(A + (size_t)(m0 + ar) * K + ac + (c << 2));
        bS[c] = ld4(W + (size_t)br * N + n0 + bc + (c << 2));
    }

    for (int k0 = 0; k0 < K; k0 += 32) {
        __syncthreads();
        #pragma unroll
        for (int c = 0; c < 4; ++c) {
            As[ac + (c << 2) + 0][ar] = aS[c].x;
            As[ac + (c << 2) + 1][ar] = aS[c].y;
            As[ac + (c << 2) + 2][ar] = aS[c].z;
            As[ac + (c << 2) + 3][ar] = aS[c].w;
            *(float4*)&Bs[br][bc + (c << 2)] = bS[c];
        }
        __syncthreads();

        if (k0 + 32 < K) {
            #pragma unroll
            for (int c = 0; c < 4; ++c) {
                aS[c] = ld4(A + (size_t)(m0 + ar) * K + k0 + 32 + ac + (c << 2));
                bS[c] = ld4(W + (size_t)(k0 + 32 + br) * N + n0 + bc + (c << 2));
            }
        }

        #pragma unroll
        for (int kk = 0; kk < 32; ++kk) {
            float4 a0 = *(const float4*)&As[kk][r8];
            float4 a1 = *(const float4*)&As[kk][r8 + 4];
            float4 b0 = *(const float4*)&Bs[kk][cl];
            float4 b1 = *(const float4*)&Bs[kk][cl + 64];
            float aa[8] = {a0.x, a0.y, a0.z, a0.w, a1.x, a1.y, a1.z, a1.w};
            float bb[8] = {b0.x, b0.y, b0.z, b0.w, b1.x, b1.y, b1.z, b1.w};
            #pragma unroll
            for (int i = 0; i < 8; ++i)
                #pragma unroll
                for (int j = 0; j < 8; ++j)
                    acc[i][j] += aa[i] * bb[j];
        }
    }

    const float scale = powf(sqrtf(Fdim) / log1pf(Fdim), *alphap);
    #pragma unroll
    for (int i = 0; i < 8; ++i) {
        const int m = m0 + r8 + i;
        const float xnm = xn[m];
        float o[8];
        #pragma unroll
        for (int j = 0; j < 8; ++j) {
            const int n = n0 + ((j < 4) ? (cl + j) : (64 + cl + j - 4));
            float d = acc[i][j];
            float den = xnm + wn[n] - 2.f * d + EPS_YAT;
            o[j] = (d * d / den + bias[n]) * scale;
        }
        float* op = out + (size_t)m * N + n0 + cl;
        *(float4*)op        = make_float4(o[0], o[1], o[2], o[3]);
        *(float4*)(op + 64) = make_float4(o[4], o[5], o[6], o[7]);
    }
}

// ======================= flash attention (yat score) ========================
// EXACT R5 version (651 us measured; WRITE 0.94 GB). R6's micro-changes (rcp,
// kns float4 hoist) doubled HBM traffic -> spill-sensitive; do not perturb
// this formulation without checking WRITE_SIZE.
__global__ __launch_bounds__(256, 3)
void yat_flash_kernel(const float* __restrict__ qkv, const float* __restrict__ qn,
                      const float* __restrict__ kn, float* __restrict__ out) {
    __shared__ __align__(16) float Qs[4096], Ks[4096], Vs[4096];
    __shared__ float kns[64];
    float* Ps = Ks;  // Ks dead once S is computed
    const int tid = threadIdx.x;
    const int L = blockIdx.x;        // 0..767
    const int qt_tab[16] = {15,0,14,1,13,2,12,3,11,4,10,5,9,6,8,7};
    const int qt = qt_tab[L / 48];
    const int bh = L % 48;
    const int h = bh % 12, b = bh / 12;
    const int lr = tid >> 4;         // 0..15
    const int lsl = tid & 15;        // float4 slot
    const int lc = lsl << 2;
    const size_t base = (size_t)b * 2359296 + h * 64;  // b*1024*2304

    #pragma unroll
    for (int l = 0; l < 4; ++l) {
        int row = lr + l * 16;
        *T4(Qs, row, lsl) = ld4(qkv + base + (size_t)((qt << 6) + row) * 2304 + lc);
    }

    const int r4 = lr << 2;          // 0..60
    const int c4 = lc;               // 0..60
    const int rs0 = lr;
    const int cs0 = lsl;
    float qnr[4];
    #pragma unroll
    for (int i = 0; i < 4; ++i) qnr[i] = qn[bh * 1024 + (qt << 6) + r4 + i];

    float acc[4][4] = {};
    float mrow[4] = {-3e38f, -3e38f, -3e38f, -3e38f};
    float lrow[4] = {0.f, 0.f, 0.f, 0.f};

    // stage kt=0 K/V into registers
    float4 kS[4], vS[4];
    #pragma unroll
    for (int l = 0; l < 4; ++l) {
        size_t rb = base + (size_t)(lr + l * 16) * 2304;
        kS[l] = ld4(qkv + rb + 768 + lc);
        vS[l] = ld4(qkv + rb + 1536 + lc);
    }
    float knS = (tid < 64) ? kn[bh * 1024 + tid] : 0.f;

    for (int kt = 0; kt <= qt; ++kt) {
        __syncthreads();  // prior PV reads (Ps=Ks, Vs) done before overwrite
        #pragma unroll
        for (int l = 0; l < 4; ++l) {
            int row = lr + l * 16;
            *T4(Ks, row, lsl) = kS[l];
            *T4(Vs, row, lsl) = vS[l];
        }
        if (tid < 64) kns[tid] = knS;
        __syncthreads();

        if (kt < qt) {  // prefetch kt+1 (block-uniform); ~full phase of slack
            #pragma unroll
            for (int l = 0; l < 4; ++l) {
                size_t rb = base + (size_t)(((kt + 1) << 6) + lr + l * 16) * 2304;
                kS[l] = ld4(qkv + rb + 768 + lc);
                vS[l] = ld4(qkv + rb + 1536 + lc);
            }
            if (tid < 64) knS = kn[bh * 1024 + ((kt + 1) << 6) + tid];
        }

        // ---- S = Q K^T ----
        float s[4][4] = {};
        #pragma unroll
        for (int d4 = 0; d4 < 16; ++d4) {
            float4 aR[4], bR[4];
            #pragma unroll
            for (int i = 0; i < 4; ++i)
                aR[i] = *(const float4*)(Qs + (r4 + i) * 64 + ((d4 ^ rs0) & 15) * 4);
            #pragma unroll
            for (int j = 0; j < 4; ++j)
                bR[j] = *(const float4*)(Ks + (c4 + j) * 64 + ((d4 ^ cs0) & 15) * 4);
            #pragma unroll
            for (int i = 0; i < 4; ++i)
                #pragma unroll
                for (int j = 0; j < 4; ++j)
                    s[i][j] += aR[i].x * bR[j].x + aR[i].y * bR[j].y +
                               aR[i].z * bR[j].z + aR[i].w * bR[j].w;
        }
        __syncthreads();  // Ks reads done; Ps may overwrite

        // ---- yat score + causal mask + online softmax; P -> LDS ----
        const bool diag = (kt == qt);
        #pragma unroll
        for (int i = 0; i < 4; ++i) {
            float mm = -3e38f;
            #pragma unroll
            for (int j = 0; j < 4; ++j) {
                float sv = s[i][j] * 0.125f;
                float den = qnr[i] + kns[c4 + j] - 2.f * sv + EPS_YAT;
                float v = sv * sv / den;
                if (diag && (c4 + j > r4 + i)) v = -3e38f;
                s[i][j] = v;
                mm = fmaxf(mm, v);
            }
            mm = fmaxf(mm, __shfl_xor(mm, 8, 16));
            mm = fmaxf(mm, __shfl_xor(mm, 4, 16));
            mm = fmaxf(mm, __shfl_xor(mm, 2, 16));
            mm = fmaxf(mm, __shfl_xor(mm, 1, 16));
            const float mnew = fmaxf(mrow[i], mm);
            const float al = __expf(mrow[i] - mnew);
            mrow[i] = mnew;
            float rs = 0.f;
            #pragma unroll
            for (int j = 0; j < 4; ++j) {
                float p = __expf(s[i][j] - mnew);  // masked -> 0
                s[i][j] = p;
                rs += p;
            }
            rs += __shfl_xor(rs, 8, 16);
            rs += __shfl_xor(rs, 4, 16);
            rs += __shfl_xor(rs, 2, 16);
            rs += __shfl_xor(rs, 1, 16);
            lrow[i] = lrow[i] * al + rs;
            acc[i][0] *= al; acc[i][1] *= al; acc[i][2] *= al; acc[i][3] *= al;
            *T4(Ps, r4 + i, lsl) = make_float4(s[i][0], s[i][1], s[i][2], s[i][3]);
        }
        __syncthreads();

        // ---- O += P V ----
        #pragma unroll
        for (int j4 = 0; j4 < 16; ++j4) {
            float4 pR[4], vR[4];
            #pragma unroll
            for (int i = 0; i < 4; ++i)
                pR[i] = *(const float4*)(Ps + (r4 + i) * 64 + ((j4 ^ rs0) & 15) * 4);
            #pragma unroll
            for (int t2 = 0; t2 < 4; ++t2)
                vR[t2] = *(const float4*)(Vs + ((j4 << 2) + t2) * 64 + ((cs0 ^ j4) & 15) * 4);
            #pragma unroll
            for (int i = 0; i < 4; ++i) {
                acc[i][0] += pR[i].x * vR[0].x + pR[i].y * vR[1].x + pR[i].z * vR[2].x + pR[i].w * vR[3].x;
                acc[i][1] += pR[i].x * vR[0].y + pR[i].y * vR[1].y + pR[i].z * vR[2].y + pR[i].w * vR[3].y;
                acc[i][2] += pR[i].x * vR[0].z + pR[i].y * vR[1].z + pR[i].z * vR[2].z + pR[i].w * vR[3].z;
                acc[i][3] += pR[i].x * vR[0].w + pR[i].y * vR[1].w + pR[i].z * vR[2].w + pR[i].w * vR[3].w;
            }
        }
    }

    #pragma unroll
    for (int i = 0; i < 4; ++i) {
        float inv = 1.f / lrow[i];
        *(float4*)(out + (size_t)(b * 1024 + (qt << 6) + r4 + i) * 768 + h * 64 + c4) =
            make_float4(acc[i][0] * inv, acc[i][1] * inv, acc[i][2] * inv, acc[i][3] * inv);
    }
}

extern "C" void kernel_launch(void* const* d_in, const int* in_sizes, int n_in,
                              void* d_out, int out_size, void* d_ws, size_t ws_size,
                              hipStream_t stream) {
    const float* x          = (const float*)d_in[0];
    // d_in[1] = mask (causal, known structure — unused)
    const float* W_attn     = (const float*)d_in[2];
    const float* b_attn     = (const float*)d_in[3];
    const float* alpha_attn = (const float*)d_in[4];
    const float* W_proj     = (const float*)d_in[5];
    const float* b_proj     = (const float*)d_in[6];
    const float* alpha_proj = (const float*)d_in[7];

    float* ws       = (float*)d_ws;
    float* qkv      = ws;                 // 4*1024*2304 = 9437184
    float* attn_out = ws + 9437184;       // 4*1024*768  = 3145728
    float* xn       = ws + 12582912;      // 4096
    float* an       = ws + 12587008;      // 4096
    float* wn_attn  = ws + 12591104;      // 2304
    float* wn_proj  = ws + 12593408;      // 768
    float* qn       = ws + 12594176;      // 49152
    float* kn       = ws + 12643328;      // 49152  (end: 12692480 floats ~50.8 MB)

    colnorm_kernel<<<36, 256, 0, stream>>>(W_attn, wn_attn, 768, 2304);
    colnorm_kernel<<<12, 256, 0, stream>>>(W_proj, wn_proj, 768, 768);
    rownorm_kernel<<<1024, 256, 0, stream>>>(x, xn, 768);
    yat_gemm_kernel<<<dim3(18, 32), 256, 0, stream>>>(
        x, W_attn, b_attn, xn, wn_attn, alpha_attn, 2304.f, qkv, 4096, 2304, 768);
    qknorm_kernel<<<6144, 256, 0, stream>>>(qkv, qn, kn);
    yat_flash_kernel<<<768, 256, 0, stream>>>(qkv, qn, kn, attn_out);
    rownorm_kernel<<<1024, 256, 0, stream>>>(attn_out, an, 768);
    yat_gemm_kernel<<<dim3(6, 32), 256, 0, stream>>>(
        attn_out, W_proj, b_proj, an, wn_proj, alpha_proj, 768.f, (float*)d_out, 4096, 768, 768);
}